// Round 14
// baseline (787.606 us; speedup 1.0000x reference)
//
#include <hip/hip_runtime.h>
#include <hip/hip_fp16.h>
#include <cstdint>

#define HIDDEN 128
#define MTOT 16

typedef float vfloat4 __attribute__((ext_vector_type(4)));

// ---------------------------------------------------------------------------
// Zero the histogram counters (n+1 ints).
// ---------------------------------------------------------------------------
__global__ __launch_bounds__(256) void zero_cnt_kernel(int* __restrict__ cnt,
                                                       int n) {
  int i = blockIdx.x * 256 + threadIdx.x;
  if (i < n) cnt[i] = 0;
}

// ---------------------------------------------------------------------------
// Histogram of dst over edges.
// ---------------------------------------------------------------------------
__global__ __launch_bounds__(256) void hist_kernel(const int* __restrict__ ei,
                                                   int E, int* __restrict__ cnt) {
  int i = blockIdx.x * 256 + threadIdx.x;
  int st = gridDim.x * 256;
  for (; i < E; i += st) atomicAdd(&cnt[ei[E + i]], 1);
}

// ---------------------------------------------------------------------------
// Single-block exclusive scan: cnt[i] (histogram) -> rowptr[i] = exclusive
// prefix; cnt[i] is overwritten with the same prefix (reused as scatter
// cursor). rowptr[n] = E.
// ---------------------------------------------------------------------------
__global__ __launch_bounds__(1024) void scan_kernel(int* __restrict__ cnt,
                                                    int* __restrict__ rowptr,
                                                    int n) {
  __shared__ int lsum[1024];
  const int t = threadIdx.x;
  const int CH = (n + 1023) / 1024;
  const int base = t * CH;
  const int end = min(base + CH, n);
  int s = 0;
  for (int i = base; i < end; ++i) s += cnt[i];
  lsum[t] = s;
  __syncthreads();
  // Hillis-Steele inclusive scan (double-barrier per step)
  for (int off = 1; off < 1024; off <<= 1) {
    int v = (t >= off) ? lsum[t - off] : 0;
    __syncthreads();
    lsum[t] += v;
    __syncthreads();
  }
  int run = (t == 0) ? 0 : lsum[t - 1];
  for (int i = base; i < end; ++i) {
    int c = cnt[i];
    rowptr[i] = run;
    cnt[i] = run;  // cursor for scatter
    run += c;
  }
  if (t == 1023) rowptr[n] = run;  // == E
}

// ---------------------------------------------------------------------------
// Scatter edges into dst-sorted record array: recs[3p]={src,e,cutoff_bits}.
// ---------------------------------------------------------------------------
__global__ __launch_bounds__(256) void scatter_kernel(
    const int* __restrict__ ei, const float* __restrict__ cutoff, int E,
    int* __restrict__ cursor, int* __restrict__ recs) {
  int e = blockIdx.x * 256 + threadIdx.x;
  int st = gridDim.x * 256;
  for (; e < E; e += st) {
    int dst = ei[E + e];
    int pos = atomicAdd(&cursor[dst], 1);
    recs[3 * pos]     = ei[e];
    recs[3 * pos + 1] = e;
    recs[3 * pos + 2] = __float_as_int(cutoff[e]);
  }
}

// ---------------------------------------------------------------------------
// q/k projection, fp16 output. W in LDS, float4-preserving XOR swizzle.
// 8-row unroll: one ds_read_b128 feeds 32 FMAs.
// ---------------------------------------------------------------------------
__global__ __launch_bounds__(256) void proj_kernel(
    const float* __restrict__ x, const float* __restrict__ W,
    __half* __restrict__ out, int n_rows, float scale) {
  __shared__ float sW[128 * 128];  // 64 KB, swizzled
  for (int i = threadIdx.x; i < 128 * 128; i += 256) {
    int j = i >> 7, d = i & 127;
    sW[j * 128 + (d ^ ((j & 7) << 2))] = W[i] * scale;
  }
  __syncthreads();

  const int col = threadIdx.x & 127;
  const int g   = threadIdx.x >> 7;
  const int sx  = (col & 7) << 2;
  const float* sWc = sW + col * 128;

  const int row0 = blockIdx.x * 64;
#pragma unroll 1
  for (int m = 0; m < 4; ++m) {
    int r0 = row0 + g * 8 + m * 16;
    if (r0 >= n_rows) break;
    const float4* x4 = (const float4*)(x + (size_t)r0 * HIDDEN);
    if (r0 + 7 < n_rows) {
      float a0 = 0.f, a1 = 0.f, a2 = 0.f, a3 = 0.f;
      float a4 = 0.f, a5 = 0.f, a6 = 0.f, a7 = 0.f;
#pragma unroll
      for (int d4 = 0; d4 < 32; ++d4) {
        float4 w4 = *(const float4*)(sWc + ((d4 << 2) ^ sx));
        float4 xv0 = x4[d4];
        float4 xv1 = x4[32 + d4];
        float4 xv2 = x4[64 + d4];
        float4 xv3 = x4[96 + d4];
        float4 xv4 = x4[128 + d4];
        float4 xv5 = x4[160 + d4];
        float4 xv6 = x4[192 + d4];
        float4 xv7 = x4[224 + d4];
        a0 += xv0.x * w4.x + xv0.y * w4.y + xv0.z * w4.z + xv0.w * w4.w;
        a1 += xv1.x * w4.x + xv1.y * w4.y + xv1.z * w4.z + xv1.w * w4.w;
        a2 += xv2.x * w4.x + xv2.y * w4.y + xv2.z * w4.z + xv2.w * w4.w;
        a3 += xv3.x * w4.x + xv3.y * w4.y + xv3.z * w4.z + xv3.w * w4.w;
        a4 += xv4.x * w4.x + xv4.y * w4.y + xv4.z * w4.z + xv4.w * w4.w;
        a5 += xv5.x * w4.x + xv5.y * w4.y + xv5.z * w4.z + xv5.w * w4.w;
        a6 += xv6.x * w4.x + xv6.y * w4.y + xv6.z * w4.z + xv6.w * w4.w;
        a7 += xv7.x * w4.x + xv7.y * w4.y + xv7.z * w4.z + xv7.w * w4.w;
      }
      out[(size_t)(r0 + 0) * HIDDEN + col] = __float2half(a0);
      out[(size_t)(r0 + 1) * HIDDEN + col] = __float2half(a1);
      out[(size_t)(r0 + 2) * HIDDEN + col] = __float2half(a2);
      out[(size_t)(r0 + 3) * HIDDEN + col] = __float2half(a3);
      out[(size_t)(r0 + 4) * HIDDEN + col] = __float2half(a4);
      out[(size_t)(r0 + 5) * HIDDEN + col] = __float2half(a5);
      out[(size_t)(r0 + 6) * HIDDEN + col] = __float2half(a6);
      out[(size_t)(r0 + 7) * HIDDEN + col] = __float2half(a7);
    } else {
      for (int r = r0; r < n_rows; ++r) {
        const float4* xr = (const float4*)(x + (size_t)r * HIDDEN);
        float a = 0.f;
        for (int d4 = 0; d4 < 32; ++d4) {
          float4 w4 = *(const float4*)(sWc + ((d4 << 2) ^ sx));
          float4 xv = xr[d4];
          a += xv.x * w4.x + xv.y * w4.y + xv.z * w4.z + xv.w * w4.w;
        }
        out[(size_t)r * HIDDEN + col] = __float2half(a);
      }
    }
  }
}

// ---------------------------------------------------------------------------
// Edge kernel, CSR: ONE WAVE PER NODE.
// - q row loaded ONCE per node (was: per edge -> 410MB of gather fills).
// - 4 edges in parallel (4 x 16-lane sub-groups); each lane covers 8 dims
//   (uint4 of fp16); head = midx>>2; reduce via shfl_xor(1,2).
// - acc[16] kept in registers per edge-slot, reduced across slots via
//   shfl_xor(16,32); ONE plain store per node. ZERO atomics, no out-zeroing.
// - k/w/sph reads become dst-ordered (random rows) -- the bet is that the
//   removed q-gather + atomic + write traffic outweighs the DRAM-order loss.
// ---------------------------------------------------------------------------
__global__ __launch_bounds__(256) void edge_kernel(
    const __half* __restrict__ q, const __half* __restrict__ k,
    const float* __restrict__ w_ij, const float* __restrict__ sph,
    const int* __restrict__ rowptr, const int* __restrict__ recs,
    float* __restrict__ out, int n_nodes) {
  const int lane = threadIdx.x & 63;
  const int sub  = lane >> 4;
  const int midx = lane & 15;
  const int gb   = lane & 48;
  // m -> head: m0->h0, m1..3->h1, m4..8->h2, m9..15->h3
  const int h_for_m = (midx >= 1) + (midx >= 4) + (midx >= 9);
  const int amLane  = gb + (h_for_m << 2);
  const int wv      = blockIdx.x * 4 + (threadIdx.x >> 6);
  const int nwaves  = gridDim.x * 4;

  for (int n = wv; n < n_nodes; n += nwaves) {
    const int rp0 = rowptr[n];
    const int rp1 = rowptr[n + 1];
    union { uint4 u; __half2 h2[4]; } qa;
    qa.u = *((const uint4*)(q + (size_t)n * HIDDEN) + midx);
    float2 q0 = __half22float2(qa.h2[0]);
    float2 q1 = __half22float2(qa.h2[1]);
    float2 q2 = __half22float2(qa.h2[2]);
    float2 q3 = __half22float2(qa.h2[3]);
    float acc = 0.f;

    for (int j0 = rp0; j0 < rp1; j0 += 4) {
      const int j = j0 + sub;
      const bool active = j < rp1;
      const int jc = active ? j : rp1 - 1;  // rp1 > rp0 inside this loop
      const int rsrc   = recs[3 * jc];
      const int re     = recs[3 * jc + 1];
      const float rcut = __int_as_float(recs[3 * jc + 2]);

      union { uint4 u; __half2 h2[4]; } ka;
      ka.u = *((const uint4*)(k + (size_t)rsrc * HIDDEN) + midx);
      const vfloat4* wp =
          (const vfloat4*)(w_ij + (size_t)re * HIDDEN) + (midx << 1);
      vfloat4 w0 = __builtin_nontemporal_load(wp);
      vfloat4 w1 = __builtin_nontemporal_load(wp + 1);
      float sp = __builtin_nontemporal_load(sph + (size_t)re * MTOT + midx);

      float2 k0 = __half22float2(ka.h2[0]);
      float2 k1 = __half22float2(ka.h2[1]);
      float2 k2 = __half22float2(ka.h2[2]);
      float2 k3 = __half22float2(ka.h2[3]);
      float p = q0.x * w0.x * k0.x + q0.y * w0.y * k0.y +
                q1.x * w0.z * k1.x + q1.y * w0.w * k1.y +
                q2.x * w1.x * k2.x + q2.y * w1.y * k2.y +
                q3.x * w1.z * k3.x + q3.y * w1.w * k3.y;
      p += __shfl_xor(p, 1);
      p += __shfl_xor(p, 2);
      float alpha = p * rcut;
      float am = __shfl(alpha, amLane);
      if (active) acc += am * sp;
    }
    // reduce the 4 edge-slots' partials
    acc += __shfl_xor(acc, 16);
    acc += __shfl_xor(acc, 32);
    if (lane < 16) out[(size_t)n * MTOT + midx] = acc;
  }
}

extern "C" void kernel_launch(void* const* d_in, const int* in_sizes, int n_in,
                              void* d_out, int out_size, void* d_ws, size_t ws_size,
                              hipStream_t stream) {
  // inputs: chi, sph_ij, x, w_ij, edge_index, cutoff, Wq, Wk
  const float* sph    = (const float*)d_in[1];
  const float* x      = (const float*)d_in[2];
  const float* w_ij   = (const float*)d_in[3];
  const int*   ei     = (const int*)d_in[4];
  const float* cutoff = (const float*)d_in[5];
  const float* Wq     = (const float*)d_in[6];
  const float* Wk     = (const float*)d_in[7];
  float* out = (float*)d_out;

  const int n_nodes = in_sizes[0] / MTOT;  // chi is [N, 16]
  const int E       = in_sizes[5];         // cutoff is [E, 1]

  // ws layout: q fp16 | k fp16 | cnt/cursor[n+1] | rowptr[n+1] | recs[3E]
  __half* q = (__half*)d_ws;
  __half* k = q + (size_t)n_nodes * HIDDEN;
  int* cnt    = (int*)(k + (size_t)n_nodes * HIDDEN);
  int* rowptr = cnt + (n_nodes + 1);
  int* recs   = rowptr + (n_nodes + 1);

  zero_cnt_kernel<<<(n_nodes + 256) / 256, 256, 0, stream>>>(cnt, n_nodes + 1);

  const int pgrid = (n_nodes + 63) / 64;
  const float inv_sqrt_hd = 0.17677669529663687f;  // 1/sqrt(32)
  proj_kernel<<<pgrid, 256, 0, stream>>>(x, Wq, q, n_nodes, inv_sqrt_hd);
  proj_kernel<<<pgrid, 256, 0, stream>>>(x, Wk, k, n_nodes, 1.0f);

  hist_kernel<<<2048, 256, 0, stream>>>(ei, E, cnt);
  scan_kernel<<<1, 1024, 0, stream>>>(cnt, rowptr, n_nodes);
  scatter_kernel<<<2048, 256, 0, stream>>>(ei, cutoff, E, cnt, recs);

  const int NB = (n_nodes + 3) / 4;  // one wave per node
  edge_kernel<<<NB, 256, 0, stream>>>(q, k, w_ij, sph, rowptr, recs, out,
                                      n_nodes);
}

// Round 15
// 479.626 us; speedup vs baseline: 1.6421x; 1.6421x over previous
//
#include <hip/hip_runtime.h>
#include <hip/hip_fp16.h>
#include <cstdint>

#define HIDDEN 128
#define MTOT 16

typedef float vfloat4 __attribute__((ext_vector_type(4)));

// ---------------------------------------------------------------------------
// Zero-fill d_out (harness poisons d_out with 0xAA; graph must re-zero).
// ---------------------------------------------------------------------------
__global__ __launch_bounds__(256) void zero_kernel(float4* __restrict__ out,
                                                   int n4) {
  int i = blockIdx.x * 256 + threadIdx.x;
  int stride = gridDim.x * 256;
  float4 z = {0.f, 0.f, 0.f, 0.f};
  for (; i < n4; i += stride) out[i] = z;
}

// ---------------------------------------------------------------------------
// q/k projection, fp16 output. W in LDS, float4-preserving XOR swizzle.
// 8-row unroll: one ds_read_b128 feeds 32 FMAs.
// ---------------------------------------------------------------------------
__global__ __launch_bounds__(256) void proj_kernel(
    const float* __restrict__ x, const float* __restrict__ W,
    __half* __restrict__ out, int n_rows, float scale) {
  __shared__ float sW[128 * 128];  // 64 KB, swizzled
  for (int i = threadIdx.x; i < 128 * 128; i += 256) {
    int j = i >> 7, d = i & 127;
    sW[j * 128 + (d ^ ((j & 7) << 2))] = W[i] * scale;
  }
  __syncthreads();

  const int col = threadIdx.x & 127;
  const int g   = threadIdx.x >> 7;
  const int sx  = (col & 7) << 2;
  const float* sWc = sW + col * 128;

  const int row0 = blockIdx.x * 64;
#pragma unroll 1
  for (int m = 0; m < 4; ++m) {
    int r0 = row0 + g * 8 + m * 16;
    if (r0 >= n_rows) break;
    const float4* x4 = (const float4*)(x + (size_t)r0 * HIDDEN);
    if (r0 + 7 < n_rows) {
      float a0 = 0.f, a1 = 0.f, a2 = 0.f, a3 = 0.f;
      float a4 = 0.f, a5 = 0.f, a6 = 0.f, a7 = 0.f;
#pragma unroll
      for (int d4 = 0; d4 < 32; ++d4) {
        float4 w4 = *(const float4*)(sWc + ((d4 << 2) ^ sx));
        float4 xv0 = x4[d4];
        float4 xv1 = x4[32 + d4];
        float4 xv2 = x4[64 + d4];
        float4 xv3 = x4[96 + d4];
        float4 xv4 = x4[128 + d4];
        float4 xv5 = x4[160 + d4];
        float4 xv6 = x4[192 + d4];
        float4 xv7 = x4[224 + d4];
        a0 += xv0.x * w4.x + xv0.y * w4.y + xv0.z * w4.z + xv0.w * w4.w;
        a1 += xv1.x * w4.x + xv1.y * w4.y + xv1.z * w4.z + xv1.w * w4.w;
        a2 += xv2.x * w4.x + xv2.y * w4.y + xv2.z * w4.z + xv2.w * w4.w;
        a3 += xv3.x * w4.x + xv3.y * w4.y + xv3.z * w4.z + xv3.w * w4.w;
        a4 += xv4.x * w4.x + xv4.y * w4.y + xv4.z * w4.z + xv4.w * w4.w;
        a5 += xv5.x * w4.x + xv5.y * w4.y + xv5.z * w4.z + xv5.w * w4.w;
        a6 += xv6.x * w4.x + xv6.y * w4.y + xv6.z * w4.z + xv6.w * w4.w;
        a7 += xv7.x * w4.x + xv7.y * w4.y + xv7.z * w4.z + xv7.w * w4.w;
      }
      out[(size_t)(r0 + 0) * HIDDEN + col] = __float2half(a0);
      out[(size_t)(r0 + 1) * HIDDEN + col] = __float2half(a1);
      out[(size_t)(r0 + 2) * HIDDEN + col] = __float2half(a2);
      out[(size_t)(r0 + 3) * HIDDEN + col] = __float2half(a3);
      out[(size_t)(r0 + 4) * HIDDEN + col] = __float2half(a4);
      out[(size_t)(r0 + 5) * HIDDEN + col] = __float2half(a5);
      out[(size_t)(r0 + 6) * HIDDEN + col] = __float2half(a6);
      out[(size_t)(r0 + 7) * HIDDEN + col] = __float2half(a7);
    } else {
      for (int r = r0; r < n_rows; ++r) {
        const float4* xr = (const float4*)(x + (size_t)r * HIDDEN);
        float a = 0.f;
        for (int d4 = 0; d4 < 32; ++d4) {
          float4 w4 = *(const float4*)(sWc + ((d4 << 2) ^ sx));
          float4 xv = xr[d4];
          a += xv.x * w4.x + xv.y * w4.y + xv.z * w4.z + xv.w * w4.w;
        }
        out[(size_t)r * HIDDEN + col] = __float2half(a);
      }
    }
  }
}

// ---------------------------------------------------------------------------
// Edge kernel (R8 body + occupancy push).
// __launch_bounds__(256, 8): cap VGPR at 64 -> 8 waves/SIMD eligible (R13's
// 68 VGPR sat just past the 64 step -> 7). NB doubled to 40000 (5 edges per
// group): more independent blocks resident per CU for latency coverage.
// R12/R13 counters: Occupancy ~33%, HBM 19%, VALU 21% -- TLP-starved is the
// last untested hypothesis.
// ---------------------------------------------------------------------------
__global__ __launch_bounds__(256, 8) void edge_kernel(
    const __half* __restrict__ q, const __half* __restrict__ k,
    const float* __restrict__ w_ij, const float* __restrict__ sph,
    const int* __restrict__ ei, const float* __restrict__ cutoff,
    float* __restrict__ out, int E, int ngroups, int nb8) {
  const int rank     = (blockIdx.x & 7) * nb8 + (blockIdx.x >> 3);
  const int gid      = rank * 8 + (threadIdx.x >> 5);
  const int lane     = threadIdx.x & 31;
  const int halfbase = threadIdx.x & 32;
  const int midx     = lane & 15;
  // m -> head: m0->h0, m1..3->h1, m4..8->h2, m9..15->h3
  const int h_for_m  = (midx >= 1) + (midx >= 4) + (midx >= 9);
  const int srcLane  = halfbase + (h_for_m << 3);

  int e = gid;
  // ---- 2-edge unrolled main loop ----
  for (; e + ngroups < E; e += 2 * ngroups) {
    const int e2 = e + ngroups;
    int srcA = ei[e];
    int dstA = ei[E + e];
    int srcB = ei[e2];
    int dstB = ei[E + e2];
    float cutA = cutoff[e];
    float cutB = cutoff[e2];
    vfloat4 wA = __builtin_nontemporal_load(
        (const vfloat4*)(w_ij + (size_t)e * HIDDEN) + lane);
    vfloat4 wB = __builtin_nontemporal_load(
        (const vfloat4*)(w_ij + (size_t)e2 * HIDDEN) + lane);
    union { uint2 u; __half2 h2[2]; } qA, kA, qB, kB;
    qA.u = *((const uint2*)(q + (size_t)dstA * HIDDEN) + lane);
    kA.u = *((const uint2*)(k + (size_t)srcA * HIDDEN) + lane);
    qB.u = *((const uint2*)(q + (size_t)dstB * HIDDEN) + lane);
    kB.u = *((const uint2*)(k + (size_t)srcB * HIDDEN) + lane);
    float spA = __builtin_nontemporal_load(sph + (size_t)e * MTOT + midx);
    float spB = __builtin_nontemporal_load(sph + (size_t)e2 * MTOT + midx);

    float2 qa01 = __half22float2(qA.h2[0]);
    float2 qa23 = __half22float2(qA.h2[1]);
    float2 ka01 = __half22float2(kA.h2[0]);
    float2 ka23 = __half22float2(kA.h2[1]);
    float pA = qa01.x * wA.x * ka01.x + qa01.y * wA.y * ka01.y +
               qa23.x * wA.z * ka23.x + qa23.y * wA.w * ka23.y;
    float2 qb01 = __half22float2(qB.h2[0]);
    float2 qb23 = __half22float2(qB.h2[1]);
    float2 kb01 = __half22float2(kB.h2[0]);
    float2 kb23 = __half22float2(kB.h2[1]);
    float pB = qb01.x * wB.x * kb01.x + qb01.y * wB.y * kb01.y +
               qb23.x * wB.z * kb23.x + qb23.y * wB.w * kb23.y;

    pA += __shfl_xor(pA, 1);
    pB += __shfl_xor(pB, 1);
    pA += __shfl_xor(pA, 2);
    pB += __shfl_xor(pB, 2);
    pA += __shfl_xor(pA, 4);
    pB += __shfl_xor(pB, 4);
    float amA = __shfl(pA * cutA, srcLane);
    float amB = __shfl(pB * cutB, srcLane);
    if (lane < 16) {
      atomicAdd(out + (size_t)dstA * MTOT + midx, amA * spA);
      atomicAdd(out + (size_t)dstB * MTOT + midx, amB * spB);
    }
  }
  // ---- remainder (single) ----
  for (; e < E; e += ngroups) {
    int src = ei[e];
    int dst = ei[E + e];
    float cut = cutoff[e];
    vfloat4 w4 = __builtin_nontemporal_load(
        (const vfloat4*)(w_ij + (size_t)e * HIDDEN) + lane);
    union { uint2 u; __half2 h2[2]; } qa, ka;
    qa.u = *((const uint2*)(q + (size_t)dst * HIDDEN) + lane);
    ka.u = *((const uint2*)(k + (size_t)src * HIDDEN) + lane);
    float sp = __builtin_nontemporal_load(sph + (size_t)e * MTOT + midx);
    float2 q01 = __half22float2(qa.h2[0]);
    float2 q23 = __half22float2(qa.h2[1]);
    float2 k01 = __half22float2(ka.h2[0]);
    float2 k23 = __half22float2(ka.h2[1]);
    float p = q01.x * w4.x * k01.x + q01.y * w4.y * k01.y +
              q23.x * w4.z * k23.x + q23.y * w4.w * k23.y;
    p += __shfl_xor(p, 1);
    p += __shfl_xor(p, 2);
    p += __shfl_xor(p, 4);
    float am = __shfl(p * cut, srcLane);
    if (lane < 16) {
      atomicAdd(out + (size_t)dst * MTOT + midx, am * sp);
    }
  }
}

extern "C" void kernel_launch(void* const* d_in, const int* in_sizes, int n_in,
                              void* d_out, int out_size, void* d_ws, size_t ws_size,
                              hipStream_t stream) {
  // inputs: chi, sph_ij, x, w_ij, edge_index, cutoff, Wq, Wk
  const float* sph    = (const float*)d_in[1];
  const float* x      = (const float*)d_in[2];
  const float* w_ij   = (const float*)d_in[3];
  const int*   ei     = (const int*)d_in[4];
  const float* cutoff = (const float*)d_in[5];
  const float* Wq     = (const float*)d_in[6];
  const float* Wk     = (const float*)d_in[7];
  float* out = (float*)d_out;

  const int n_nodes = in_sizes[0] / MTOT;  // chi is [N, 16]
  const int E       = in_sizes[5];         // cutoff is [E, 1]

  __half* q = (__half*)d_ws;
  __half* k = q + (size_t)n_nodes * HIDDEN;

  const int n4 = out_size / 4;
  zero_kernel<<<256, 256, 0, stream>>>((float4*)out, n4);

  const int pgrid = (n_nodes + 63) / 64;
  const float inv_sqrt_hd = 0.17677669529663687f;  // 1/sqrt(32)
  proj_kernel<<<pgrid, 256, 0, stream>>>(x, Wq, q, n_nodes, inv_sqrt_hd);
  proj_kernel<<<pgrid, 256, 0, stream>>>(x, Wk, k, n_nodes, 1.0f);

  const int NB = 40000;  // 2x blocks; 320000 groups, 5 edges each
  const int ngroups = NB * 8;
  edge_kernel<<<NB, 256, 0, stream>>>(q, k, w_ij, sph, ei, cutoff, out, E,
                                      ngroups, NB / 8);
}

// Round 16
// 285.089 us; speedup vs baseline: 2.7627x; 1.6824x over previous
//
#include <hip/hip_runtime.h>
#include <hip/hip_fp16.h>
#include <cstdint>

#define HIDDEN 128
#define MTOT 16

typedef float vfloat4 __attribute__((ext_vector_type(4)));
typedef _Float16 f16x8 __attribute__((ext_vector_type(8)));
typedef float f32x4 __attribute__((ext_vector_type(4)));

// ---------------------------------------------------------------------------
// Zero-fill d_out (harness poisons d_out with 0xAA; graph must re-zero).
// ---------------------------------------------------------------------------
__global__ __launch_bounds__(256) void zero_kernel(float4* __restrict__ out,
                                                   int n4) {
  int i = blockIdx.x * 256 + threadIdx.x;
  int stride = gridDim.x * 256;
  float4 z = {0.f, 0.f, 0.f, 0.f};
  for (; i < n4; i += stride) out[i] = z;
}

// ---------------------------------------------------------------------------
// x fp32 -> fp16 (8 elems/thread, vectorized).
// ---------------------------------------------------------------------------
__global__ __launch_bounds__(256) void cvt_x_kernel(
    const float* __restrict__ x, __half* __restrict__ xh, int n8) {
  int i = blockIdx.x * 256 + threadIdx.x;
  int stride = gridDim.x * 256;
  for (; i < n8; i += stride) {
    const float4* src = (const float4*)(x + (size_t)i * 8);
    float4 v0 = src[0];
    float4 v1 = src[1];
    __half2 h[4];
    h[0] = __floats2half2_rn(v0.x, v0.y);
    h[1] = __floats2half2_rn(v0.z, v0.w);
    h[2] = __floats2half2_rn(v1.x, v1.y);
    h[3] = __floats2half2_rn(v1.z, v1.w);
    *(uint4*)(xh + (size_t)i * 8) = *(uint4*)h;
  }
}

// ---------------------------------------------------------------------------
// Pack [Wq*scale ; Wk] -> Wh fp16 (256 rows x 128). 32768 elems.
// ---------------------------------------------------------------------------
__global__ __launch_bounds__(256) void cvt_w_kernel(
    const float* __restrict__ Wq, const float* __restrict__ Wk,
    __half* __restrict__ Wh, float scale) {
  int idx = blockIdx.x * 256 + threadIdx.x;
  if (idx >= 256 * 128) return;
  int j = idx >> 7, d = idx & 127;
  float v = (j < 128) ? Wq[j * 128 + d] * scale : Wk[(j - 128) * 128 + d];
  Wh[idx] = __float2half(v);
}

// ---------------------------------------------------------------------------
// Fused q/k projection via MFMA: D[M=50000, N=256] = x_h @ Wh^T.
// N cols 0..127 -> q, 128..255 -> k. No LDS; Wh (64KB) is L2-resident.
// Per wave: 16-row strip; A-frags (4 k-steps) kept resident; loop 16 j-tiles
// {4 B-frag loads, 4 mfma_f32_16x16x32_f16, 4 predicated fp16 stores}.
// Layouts (gfx950): A/B lane l -> (idx=l&15, 8 consecutive k at (l>>4)*8);
// C/D: col=l&15, row=(l>>4)*4+reg [verified mapping].
// ---------------------------------------------------------------------------
__global__ __launch_bounds__(256) void proj_mfma_kernel(
    const __half* __restrict__ xh, const __half* __restrict__ Wh,
    __half* __restrict__ q, __half* __restrict__ k, int n_rows) {
  const int wave = threadIdx.x >> 6;
  const int lane = threadIdx.x & 63;
  const int row_in = lane & 15;
  const int kgrp = lane >> 4;
  const int r0 = blockIdx.x * 64 + wave * 16;
  if (r0 >= n_rows) return;

  // A fragments: x_h[r0+row_in][kgrp*8 + 32*ks .. +8]
  const int ar = min(r0 + row_in, n_rows - 1);
  const __half* xrow = xh + (size_t)ar * HIDDEN + kgrp * 8;
  f16x8 a0 = *(const f16x8*)(xrow);
  f16x8 a1 = *(const f16x8*)(xrow + 32);
  f16x8 a2 = *(const f16x8*)(xrow + 64);
  f16x8 a3 = *(const f16x8*)(xrow + 96);

  const int orow0 = r0 + kgrp * 4;  // output rows orow0..orow0+3

#pragma unroll
  for (int jt = 0; jt < 16; ++jt) {
    const int j = jt * 16 + row_in;  // 0..255
    const __half* wrow = Wh + (size_t)j * HIDDEN + kgrp * 8;
    f16x8 b0 = *(const f16x8*)(wrow);
    f16x8 b1 = *(const f16x8*)(wrow + 32);
    f16x8 b2 = *(const f16x8*)(wrow + 64);
    f16x8 b3 = *(const f16x8*)(wrow + 96);
    f32x4 c = {0.f, 0.f, 0.f, 0.f};
    c = __builtin_amdgcn_mfma_f32_16x16x32_f16(a0, b0, c, 0, 0, 0);
    c = __builtin_amdgcn_mfma_f32_16x16x32_f16(a1, b1, c, 0, 0, 0);
    c = __builtin_amdgcn_mfma_f32_16x16x32_f16(a2, b2, c, 0, 0, 0);
    c = __builtin_amdgcn_mfma_f32_16x16x32_f16(a3, b3, c, 0, 0, 0);
    // D element (row = (lane>>4)*4 + i, col = lane&15) of this 16x16 j-tile.
    // col j < 128 -> q col j ; else k col j-128.
    __half* outp = (j < 128) ? (q + j) : (k + (j - 128));
#pragma unroll
    for (int i = 0; i < 4; ++i) {
      int rr = orow0 + i;
      if (rr < n_rows) outp[(size_t)rr * HIDDEN] = __float2half(c[i]);
    }
  }
}

// ---------------------------------------------------------------------------
// Edge kernel (R15: R8 body + launch_bounds(256,8) + NB=40000). Best: 479.6.
// ---------------------------------------------------------------------------
__global__ __launch_bounds__(256, 8) void edge_kernel(
    const __half* __restrict__ q, const __half* __restrict__ k,
    const float* __restrict__ w_ij, const float* __restrict__ sph,
    const int* __restrict__ ei, const float* __restrict__ cutoff,
    float* __restrict__ out, int E, int ngroups, int nb8) {
  const int rank     = (blockIdx.x & 7) * nb8 + (blockIdx.x >> 3);
  const int gid      = rank * 8 + (threadIdx.x >> 5);
  const int lane     = threadIdx.x & 31;
  const int halfbase = threadIdx.x & 32;
  const int midx     = lane & 15;
  // m -> head: m0->h0, m1..3->h1, m4..8->h2, m9..15->h3
  const int h_for_m  = (midx >= 1) + (midx >= 4) + (midx >= 9);
  const int srcLane  = halfbase + (h_for_m << 3);

  int e = gid;
  for (; e + ngroups < E; e += 2 * ngroups) {
    const int e2 = e + ngroups;
    int srcA = ei[e];
    int dstA = ei[E + e];
    int srcB = ei[e2];
    int dstB = ei[E + e2];
    float cutA = cutoff[e];
    float cutB = cutoff[e2];
    vfloat4 wA = __builtin_nontemporal_load(
        (const vfloat4*)(w_ij + (size_t)e * HIDDEN) + lane);
    vfloat4 wB = __builtin_nontemporal_load(
        (const vfloat4*)(w_ij + (size_t)e2 * HIDDEN) + lane);
    union { uint2 u; __half2 h2[2]; } qA, kA, qB, kB;
    qA.u = *((const uint2*)(q + (size_t)dstA * HIDDEN) + lane);
    kA.u = *((const uint2*)(k + (size_t)srcA * HIDDEN) + lane);
    qB.u = *((const uint2*)(q + (size_t)dstB * HIDDEN) + lane);
    kB.u = *((const uint2*)(k + (size_t)srcB * HIDDEN) + lane);
    float spA = __builtin_nontemporal_load(sph + (size_t)e * MTOT + midx);
    float spB = __builtin_nontemporal_load(sph + (size_t)e2 * MTOT + midx);

    float2 qa01 = __half22float2(qA.h2[0]);
    float2 qa23 = __half22float2(qA.h2[1]);
    float2 ka01 = __half22float2(kA.h2[0]);
    float2 ka23 = __half22float2(kA.h2[1]);
    float pA = qa01.x * wA.x * ka01.x + qa01.y * wA.y * ka01.y +
               qa23.x * wA.z * ka23.x + qa23.y * wA.w * ka23.y;
    float2 qb01 = __half22float2(qB.h2[0]);
    float2 qb23 = __half22float2(qB.h2[1]);
    float2 kb01 = __half22float2(kB.h2[0]);
    float2 kb23 = __half22float2(kB.h2[1]);
    float pB = qb01.x * wB.x * kb01.x + qb01.y * wB.y * kb01.y +
               qb23.x * wB.z * kb23.x + qb23.y * wB.w * kb23.y;

    pA += __shfl_xor(pA, 1);
    pB += __shfl_xor(pB, 1);
    pA += __shfl_xor(pA, 2);
    pB += __shfl_xor(pB, 2);
    pA += __shfl_xor(pA, 4);
    pB += __shfl_xor(pB, 4);
    float amA = __shfl(pA * cutA, srcLane);
    float amB = __shfl(pB * cutB, srcLane);
    if (lane < 16) {
      atomicAdd(out + (size_t)dstA * MTOT + midx, amA * spA);
      atomicAdd(out + (size_t)dstB * MTOT + midx, amB * spB);
    }
  }
  for (; e < E; e += ngroups) {
    int src = ei[e];
    int dst = ei[E + e];
    float cut = cutoff[e];
    vfloat4 w4 = __builtin_nontemporal_load(
        (const vfloat4*)(w_ij + (size_t)e * HIDDEN) + lane);
    union { uint2 u; __half2 h2[2]; } qa, ka;
    qa.u = *((const uint2*)(q + (size_t)dst * HIDDEN) + lane);
    ka.u = *((const uint2*)(k + (size_t)src * HIDDEN) + lane);
    float sp = __builtin_nontemporal_load(sph + (size_t)e * MTOT + midx);
    float2 q01 = __half22float2(qa.h2[0]);
    float2 q23 = __half22float2(qa.h2[1]);
    float2 k01 = __half22float2(ka.h2[0]);
    float2 k23 = __half22float2(ka.h2[1]);
    float p = q01.x * w4.x * k01.x + q01.y * w4.y * k01.y +
              q23.x * w4.z * k23.x + q23.y * w4.w * k23.y;
    p += __shfl_xor(p, 1);
    p += __shfl_xor(p, 2);
    p += __shfl_xor(p, 4);
    float am = __shfl(p * cut, srcLane);
    if (lane < 16) {
      atomicAdd(out + (size_t)dst * MTOT + midx, am * sp);
    }
  }
}

extern "C" void kernel_launch(void* const* d_in, const int* in_sizes, int n_in,
                              void* d_out, int out_size, void* d_ws, size_t ws_size,
                              hipStream_t stream) {
  // inputs: chi, sph_ij, x, w_ij, edge_index, cutoff, Wq, Wk
  const float* sph    = (const float*)d_in[1];
  const float* x      = (const float*)d_in[2];
  const float* w_ij   = (const float*)d_in[3];
  const int*   ei     = (const int*)d_in[4];
  const float* cutoff = (const float*)d_in[5];
  const float* Wq     = (const float*)d_in[6];
  const float* Wk     = (const float*)d_in[7];
  float* out = (float*)d_out;

  const int n_nodes = in_sizes[0] / MTOT;  // chi is [N, 16]
  const int E       = in_sizes[5];         // cutoff is [E, 1]

  // ws: q fp16 (12.8MB) | k fp16 (12.8MB) | x_h fp16 (12.8MB) | Wh (64KB)
  __half* q  = (__half*)d_ws;
  __half* k  = q + (size_t)n_nodes * HIDDEN;
  __half* xh = k + (size_t)n_nodes * HIDDEN;
  __half* Wh = xh + (size_t)n_nodes * HIDDEN;

  const int n4 = out_size / 4;
  zero_kernel<<<256, 256, 0, stream>>>((float4*)out, n4);

  const int n8 = n_nodes * HIDDEN / 8;
  cvt_x_kernel<<<2048, 256, 0, stream>>>(x, xh, n8);
  const float inv_sqrt_hd = 0.17677669529663687f;  // 1/sqrt(32)
  cvt_w_kernel<<<128, 256, 0, stream>>>(Wq, Wk, Wh, inv_sqrt_hd);

  const int pgrid = (n_nodes + 63) / 64;
  proj_mfma_kernel<<<pgrid, 256, 0, stream>>>(xh, Wh, q, k, n_nodes);

  const int NB = 40000;  // 320000 groups, 5 edges each
  const int ngroups = NB * 8;
  edge_kernel<<<NB, 256, 0, stream>>>(q, k, w_ij, sph, ei, cutoff, out, E,
                                      ngroups, NB / 8);
}

// Round 17
// 281.902 us; speedup vs baseline: 2.7939x; 1.0113x over previous
//
#include <hip/hip_runtime.h>
#include <hip/hip_fp16.h>
#include <cstdint>

#define HIDDEN 128
#define MTOT 16

typedef float vfloat4 __attribute__((ext_vector_type(4)));
typedef _Float16 f16x8 __attribute__((ext_vector_type(8)));
typedef float f32x4 __attribute__((ext_vector_type(4)));

// ---------------------------------------------------------------------------
// Zero-fill d_out (harness poisons d_out with 0xAA; graph must re-zero).
// ---------------------------------------------------------------------------
__global__ __launch_bounds__(256) void zero_kernel(float4* __restrict__ out,
                                                   int n4) {
  int i = blockIdx.x * 256 + threadIdx.x;
  int stride = gridDim.x * 256;
  float4 z = {0.f, 0.f, 0.f, 0.f};
  for (; i < n4; i += stride) out[i] = z;
}

// ---------------------------------------------------------------------------
// Pack [Wq*scale ; Wk] -> Wh fp16 (256 rows x 128). 32768 elems.
// ---------------------------------------------------------------------------
__global__ __launch_bounds__(256) void cvt_w_kernel(
    const float* __restrict__ Wq, const float* __restrict__ Wk,
    __half* __restrict__ Wh, float scale) {
  int idx = blockIdx.x * 256 + threadIdx.x;
  if (idx >= 256 * 128) return;
  int j = idx >> 7, d = idx & 127;
  float v = (j < 128) ? Wq[j * 128 + d] * scale : Wk[(j - 128) * 128 + d];
  Wh[idx] = __float2half(v);
}

// ---------------------------------------------------------------------------
// Fused q/k projection via MFMA, x converted in-register (no xh roundtrip):
// D[M=50000, N=256] = fp16(x) @ Wh^T. N cols 0..127 -> q, 128..255 -> k.
// No LDS; Wh (64KB) is L2-resident broadcast.
// Layouts (gfx950): A/B lane l -> (idx=l&15, 8 consecutive k at (l>>4)*8);
// C/D: col=l&15, row=(l>>4)*4+reg [verified mapping].
// ---------------------------------------------------------------------------
__device__ __forceinline__ f16x8 load_cvt_frag(const float* p) {
  float4 v0 = *(const float4*)(p);
  float4 v1 = *(const float4*)(p + 4);
  __half2 h[4];
  h[0] = __floats2half2_rn(v0.x, v0.y);
  h[1] = __floats2half2_rn(v0.z, v0.w);
  h[2] = __floats2half2_rn(v1.x, v1.y);
  h[3] = __floats2half2_rn(v1.z, v1.w);
  union { __half2 hh[4]; f16x8 f; } u;
  u.hh[0] = h[0]; u.hh[1] = h[1]; u.hh[2] = h[2]; u.hh[3] = h[3];
  return u.f;
}

__global__ __launch_bounds__(256) void proj_mfma_kernel(
    const float* __restrict__ x, const __half* __restrict__ Wh,
    __half* __restrict__ q, __half* __restrict__ k, int n_rows) {
  const int wave = threadIdx.x >> 6;
  const int lane = threadIdx.x & 63;
  const int row_in = lane & 15;
  const int kgrp = lane >> 4;
  const int r0 = blockIdx.x * 64 + wave * 16;
  if (r0 >= n_rows) return;

  // A fragments: fp16(x[r0+row_in][kgrp*8 + 32*ks .. +8]) packed in-register
  const int ar = min(r0 + row_in, n_rows - 1);
  const float* xrow = x + (size_t)ar * HIDDEN + kgrp * 8;
  f16x8 a0 = load_cvt_frag(xrow);
  f16x8 a1 = load_cvt_frag(xrow + 32);
  f16x8 a2 = load_cvt_frag(xrow + 64);
  f16x8 a3 = load_cvt_frag(xrow + 96);

  const int orow0 = r0 + kgrp * 4;  // output rows orow0..orow0+3

#pragma unroll
  for (int jt = 0; jt < 16; ++jt) {
    const int j = jt * 16 + row_in;  // 0..255
    const __half* wrow = Wh + (size_t)j * HIDDEN + kgrp * 8;
    f16x8 b0 = *(const f16x8*)(wrow);
    f16x8 b1 = *(const f16x8*)(wrow + 32);
    f16x8 b2 = *(const f16x8*)(wrow + 64);
    f16x8 b3 = *(const f16x8*)(wrow + 96);
    f32x4 c = {0.f, 0.f, 0.f, 0.f};
    c = __builtin_amdgcn_mfma_f32_16x16x32_f16(a0, b0, c, 0, 0, 0);
    c = __builtin_amdgcn_mfma_f32_16x16x32_f16(a1, b1, c, 0, 0, 0);
    c = __builtin_amdgcn_mfma_f32_16x16x32_f16(a2, b2, c, 0, 0, 0);
    c = __builtin_amdgcn_mfma_f32_16x16x32_f16(a3, b3, c, 0, 0, 0);
    // D element (row = (lane>>4)*4 + i, col = lane&15) of this 16x16 j-tile.
    __half* outp = (j < 128) ? (q + j) : (k + (j - 128));
#pragma unroll
    for (int i = 0; i < 4; ++i) {
      int rr = orow0 + i;
      if (rr < n_rows) outp[(size_t)rr * HIDDEN] = __float2half(c[i]);
    }
  }
}

// ---------------------------------------------------------------------------
// Edge kernel (R15: R8 body + launch_bounds(256,8) + NB=40000). Floor-pinned:
// 8 structural levers (privatization, bucketing, pk-atomics, preload,
// inst-rate, phasing, ILP, TLP) all null or regressed. ~240us at 3.9TB/s HBM
// + 820MB gather-fill + 102MB atomic writes concurrently.
// ---------------------------------------------------------------------------
__global__ __launch_bounds__(256, 8) void edge_kernel(
    const __half* __restrict__ q, const __half* __restrict__ k,
    const float* __restrict__ w_ij, const float* __restrict__ sph,
    const int* __restrict__ ei, const float* __restrict__ cutoff,
    float* __restrict__ out, int E, int ngroups, int nb8) {
  const int rank     = (blockIdx.x & 7) * nb8 + (blockIdx.x >> 3);
  const int gid      = rank * 8 + (threadIdx.x >> 5);
  const int lane     = threadIdx.x & 31;
  const int halfbase = threadIdx.x & 32;
  const int midx     = lane & 15;
  // m -> head: m0->h0, m1..3->h1, m4..8->h2, m9..15->h3
  const int h_for_m  = (midx >= 1) + (midx >= 4) + (midx >= 9);
  const int srcLane  = halfbase + (h_for_m << 3);

  int e = gid;
  for (; e + ngroups < E; e += 2 * ngroups) {
    const int e2 = e + ngroups;
    int srcA = ei[e];
    int dstA = ei[E + e];
    int srcB = ei[e2];
    int dstB = ei[E + e2];
    float cutA = cutoff[e];
    float cutB = cutoff[e2];
    vfloat4 wA = __builtin_nontemporal_load(
        (const vfloat4*)(w_ij + (size_t)e * HIDDEN) + lane);
    vfloat4 wB = __builtin_nontemporal_load(
        (const vfloat4*)(w_ij + (size_t)e2 * HIDDEN) + lane);
    union { uint2 u; __half2 h2[2]; } qA, kA, qB, kB;
    qA.u = *((const uint2*)(q + (size_t)dstA * HIDDEN) + lane);
    kA.u = *((const uint2*)(k + (size_t)srcA * HIDDEN) + lane);
    qB.u = *((const uint2*)(q + (size_t)dstB * HIDDEN) + lane);
    kB.u = *((const uint2*)(k + (size_t)srcB * HIDDEN) + lane);
    float spA = __builtin_nontemporal_load(sph + (size_t)e * MTOT + midx);
    float spB = __builtin_nontemporal_load(sph + (size_t)e2 * MTOT + midx);

    float2 qa01 = __half22float2(qA.h2[0]);
    float2 qa23 = __half22float2(qA.h2[1]);
    float2 ka01 = __half22float2(kA.h2[0]);
    float2 ka23 = __half22float2(kA.h2[1]);
    float pA = qa01.x * wA.x * ka01.x + qa01.y * wA.y * ka01.y +
               qa23.x * wA.z * ka23.x + qa23.y * wA.w * ka23.y;
    float2 qb01 = __half22float2(qB.h2[0]);
    float2 qb23 = __half22float2(qB.h2[1]);
    float2 kb01 = __half22float2(kB.h2[0]);
    float2 kb23 = __half22float2(kB.h2[1]);
    float pB = qb01.x * wB.x * kb01.x + qb01.y * wB.y * kb01.y +
               qb23.x * wB.z * kb23.x + qb23.y * wB.w * kb23.y;

    pA += __shfl_xor(pA, 1);
    pB += __shfl_xor(pB, 1);
    pA += __shfl_xor(pA, 2);
    pB += __shfl_xor(pB, 2);
    pA += __shfl_xor(pA, 4);
    pB += __shfl_xor(pB, 4);
    float amA = __shfl(pA * cutA, srcLane);
    float amB = __shfl(pB * cutB, srcLane);
    if (lane < 16) {
      atomicAdd(out + (size_t)dstA * MTOT + midx, amA * spA);
      atomicAdd(out + (size_t)dstB * MTOT + midx, amB * spB);
    }
  }
  for (; e < E; e += ngroups) {
    int src = ei[e];
    int dst = ei[E + e];
    float cut = cutoff[e];
    vfloat4 w4 = __builtin_nontemporal_load(
        (const vfloat4*)(w_ij + (size_t)e * HIDDEN) + lane);
    union { uint2 u; __half2 h2[2]; } qa, ka;
    qa.u = *((const uint2*)(q + (size_t)dst * HIDDEN) + lane);
    ka.u = *((const uint2*)(k + (size_t)src * HIDDEN) + lane);
    float sp = __builtin_nontemporal_load(sph + (size_t)e * MTOT + midx);
    float2 q01 = __half22float2(qa.h2[0]);
    float2 q23 = __half22float2(qa.h2[1]);
    float2 k01 = __half22float2(ka.h2[0]);
    float2 k23 = __half22float2(ka.h2[1]);
    float p = q01.x * w4.x * k01.x + q01.y * w4.y * k01.y +
              q23.x * w4.z * k23.x + q23.y * w4.w * k23.y;
    p += __shfl_xor(p, 1);
    p += __shfl_xor(p, 2);
    p += __shfl_xor(p, 4);
    float am = __shfl(p * cut, srcLane);
    if (lane < 16) {
      atomicAdd(out + (size_t)dst * MTOT + midx, am * sp);
    }
  }
}

extern "C" void kernel_launch(void* const* d_in, const int* in_sizes, int n_in,
                              void* d_out, int out_size, void* d_ws, size_t ws_size,
                              hipStream_t stream) {
  // inputs: chi, sph_ij, x, w_ij, edge_index, cutoff, Wq, Wk
  const float* sph    = (const float*)d_in[1];
  const float* x      = (const float*)d_in[2];
  const float* w_ij   = (const float*)d_in[3];
  const int*   ei     = (const int*)d_in[4];
  const float* cutoff = (const float*)d_in[5];
  const float* Wq     = (const float*)d_in[6];
  const float* Wk     = (const float*)d_in[7];
  float* out = (float*)d_out;

  const int n_nodes = in_sizes[0] / MTOT;  // chi is [N, 16]
  const int E       = in_sizes[5];         // cutoff is [E, 1]

  // ws: q fp16 (12.8MB) | k fp16 (12.8MB) | Wh (64KB)
  __half* q  = (__half*)d_ws;
  __half* k  = q + (size_t)n_nodes * HIDDEN;
  __half* Wh = k + (size_t)n_nodes * HIDDEN;

  const int n4 = out_size / 4;
  zero_kernel<<<256, 256, 0, stream>>>((float4*)out, n4);

  const float inv_sqrt_hd = 0.17677669529663687f;  // 1/sqrt(32)
  cvt_w_kernel<<<128, 256, 0, stream>>>(Wq, Wk, Wh, inv_sqrt_hd);

  const int pgrid = (n_nodes + 63) / 64;
  proj_mfma_kernel<<<pgrid, 256, 0, stream>>>(x, Wh, q, k, n_nodes);

  const int NB = 40000;  // 320000 groups, 5 edges each
  const int ngroups = NB * 8;
  edge_kernel<<<NB, 256, 0, stream>>>(q, k, w_ij, sph, ei, cutoff, out, E,
                                      ngroups, NB / 8);
}

// Round 18
// 280.601 us; speedup vs baseline: 2.8069x; 1.0046x over previous
//
#include <hip/hip_runtime.h>
#include <hip/hip_fp16.h>
#include <cstdint>

#define HIDDEN 128
#define MTOT 16

typedef float vfloat4 __attribute__((ext_vector_type(4)));
typedef _Float16 f16x8 __attribute__((ext_vector_type(8)));
typedef float f32x4 __attribute__((ext_vector_type(4)));

// ---------------------------------------------------------------------------
// Zero-fill d_out (harness poisons d_out with 0xAA; graph must re-zero).
// ---------------------------------------------------------------------------
__global__ __launch_bounds__(256) void zero_kernel(float4* __restrict__ out,
                                                   int n4) {
  int i = blockIdx.x * 256 + threadIdx.x;
  int stride = gridDim.x * 256;
  float4 z = {0.f, 0.f, 0.f, 0.f};
  for (; i < n4; i += stride) out[i] = z;
}

// ---------------------------------------------------------------------------
// Pack [Wq*scale ; Wk] -> Wh fp16 (256 rows x 128). 32768 elems.
// ---------------------------------------------------------------------------
__global__ __launch_bounds__(256) void cvt_w_kernel(
    const float* __restrict__ Wq, const float* __restrict__ Wk,
    __half* __restrict__ Wh, float scale) {
  int idx = blockIdx.x * 256 + threadIdx.x;
  if (idx >= 256 * 128) return;
  int j = idx >> 7, d = idx & 127;
  float v = (j < 128) ? Wq[j * 128 + d] * scale : Wk[(j - 128) * 128 + d];
  Wh[idx] = __float2half(v);
}

// ---------------------------------------------------------------------------
// Fused q/k projection via MFMA, x converted in-register; LDS-staged
// coalesced epilogue (R17 wrote D as 2B scalar stores -> store-inst bound).
// D[M, N=256] = fp16(x) @ Wh^T; cols 0..127 -> q, 128..255 -> k.
// Each wave stages its 16x256 fp16 strip in a private 8KB LDS slice, then
// writes 8 x uint4 per lane (1KB per instruction, fully coalesced).
// Layouts (gfx950): A/B lane l -> (idx=l&15, 8 consecutive k at (l>>4)*8);
// C/D: col=l&15, row=(l>>4)*4+reg [verified mapping].
// ---------------------------------------------------------------------------
__device__ __forceinline__ f16x8 load_cvt_frag(const float* p) {
  float4 v0 = *(const float4*)(p);
  float4 v1 = *(const float4*)(p + 4);
  __half2 h[4];
  h[0] = __floats2half2_rn(v0.x, v0.y);
  h[1] = __floats2half2_rn(v0.z, v0.w);
  h[2] = __floats2half2_rn(v1.x, v1.y);
  h[3] = __floats2half2_rn(v1.z, v1.w);
  union { __half2 hh[4]; f16x8 f; } u;
  u.hh[0] = h[0]; u.hh[1] = h[1]; u.hh[2] = h[2]; u.hh[3] = h[3];
  return u.f;
}

__global__ __launch_bounds__(256) void proj_mfma_kernel(
    const float* __restrict__ x, const __half* __restrict__ Wh,
    __half* __restrict__ q, __half* __restrict__ k, int n_rows) {
  __shared__ __half tile[4][16][256];  // 8KB per wave, wave-private slice
  const int wave = threadIdx.x >> 6;
  const int lane = threadIdx.x & 63;
  const int row_in = lane & 15;
  const int kgrp = lane >> 4;
  const int r0 = blockIdx.x * 64 + wave * 16;
  if (r0 >= n_rows) return;

  // A fragments: fp16(x[r0+row_in][kgrp*8 + 32*ks .. +8]) packed in-register
  const int ar = min(r0 + row_in, n_rows - 1);
  const float* xrow = x + (size_t)ar * HIDDEN + kgrp * 8;
  f16x8 a0 = load_cvt_frag(xrow);
  f16x8 a1 = load_cvt_frag(xrow + 32);
  f16x8 a2 = load_cvt_frag(xrow + 64);
  f16x8 a3 = load_cvt_frag(xrow + 96);

#pragma unroll
  for (int jt = 0; jt < 16; ++jt) {
    const int j = jt * 16 + row_in;  // 0..255
    const __half* wrow = Wh + (size_t)j * HIDDEN + kgrp * 8;
    f16x8 b0 = *(const f16x8*)(wrow);
    f16x8 b1 = *(const f16x8*)(wrow + 32);
    f16x8 b2 = *(const f16x8*)(wrow + 64);
    f16x8 b3 = *(const f16x8*)(wrow + 96);
    f32x4 c = {0.f, 0.f, 0.f, 0.f};
    c = __builtin_amdgcn_mfma_f32_16x16x32_f16(a0, b0, c, 0, 0, 0);
    c = __builtin_amdgcn_mfma_f32_16x16x32_f16(a1, b1, c, 0, 0, 0);
    c = __builtin_amdgcn_mfma_f32_16x16x32_f16(a2, b2, c, 0, 0, 0);
    c = __builtin_amdgcn_mfma_f32_16x16x32_f16(a3, b3, c, 0, 0, 0);
    // D(row=(lane>>4)*4+i, col=lane&15) -> stage in LDS strip
#pragma unroll
    for (int i = 0; i < 4; ++i) {
      tile[wave][kgrp * 4 + i][jt * 16 + row_in] = __float2half(c[i]);
    }
  }

  // coalesced write-out: 16 rows x 256 halves = 512 uint4; 8 per lane.
  // (wave-private LDS slice: compiler-inserted lgkmcnt ordering suffices)
  const __half* src = &tile[wave][0][0];
#pragma unroll
  for (int cc = 0; cc < 8; ++cc) {
    int flat = cc * 64 + lane;
    int row16 = flat >> 5;        // 32 uint4 per row
    int seg = flat & 31;
    int rr = r0 + row16;
    if (rr < n_rows) {
      uint4 v = *(const uint4*)(src + row16 * 256 + seg * 8);
      int ch = seg * 8;
      __half* dst = (ch < 128) ? (q + (size_t)rr * HIDDEN + ch)
                               : (k + (size_t)rr * HIDDEN + ch - 128);
      *(uint4*)dst = v;
    }
  }
}

// ---------------------------------------------------------------------------
// Edge kernel (R15: R8 body + launch_bounds(256,8) + NB=40000). Floor-pinned:
// 8 structural levers (privatization, bucketing, pk-atomics, preload,
// inst-rate, phasing, ILP, TLP) all null or regressed. ~240us at 3.9TB/s HBM
// + 820MB gather-fill + 102MB atomic writes concurrently.
// ---------------------------------------------------------------------------
__global__ __launch_bounds__(256, 8) void edge_kernel(
    const __half* __restrict__ q, const __half* __restrict__ k,
    const float* __restrict__ w_ij, const float* __restrict__ sph,
    const int* __restrict__ ei, const float* __restrict__ cutoff,
    float* __restrict__ out, int E, int ngroups, int nb8) {
  const int rank     = (blockIdx.x & 7) * nb8 + (blockIdx.x >> 3);
  const int gid      = rank * 8 + (threadIdx.x >> 5);
  const int lane     = threadIdx.x & 31;
  const int halfbase = threadIdx.x & 32;
  const int midx     = lane & 15;
  // m -> head: m0->h0, m1..3->h1, m4..8->h2, m9..15->h3
  const int h_for_m  = (midx >= 1) + (midx >= 4) + (midx >= 9);
  const int srcLane  = halfbase + (h_for_m << 3);

  int e = gid;
  for (; e + ngroups < E; e += 2 * ngroups) {
    const int e2 = e + ngroups;
    int srcA = ei[e];
    int dstA = ei[E + e];
    int srcB = ei[e2];
    int dstB = ei[E + e2];
    float cutA = cutoff[e];
    float cutB = cutoff[e2];
    vfloat4 wA = __builtin_nontemporal_load(
        (const vfloat4*)(w_ij + (size_t)e * HIDDEN) + lane);
    vfloat4 wB = __builtin_nontemporal_load(
        (const vfloat4*)(w_ij + (size_t)e2 * HIDDEN) + lane);
    union { uint2 u; __half2 h2[2]; } qA, kA, qB, kB;
    qA.u = *((const uint2*)(q + (size_t)dstA * HIDDEN) + lane);
    kA.u = *((const uint2*)(k + (size_t)srcA * HIDDEN) + lane);
    qB.u = *((const uint2*)(q + (size_t)dstB * HIDDEN) + lane);
    kB.u = *((const uint2*)(k + (size_t)srcB * HIDDEN) + lane);
    float spA = __builtin_nontemporal_load(sph + (size_t)e * MTOT + midx);
    float spB = __builtin_nontemporal_load(sph + (size_t)e2 * MTOT + midx);

    float2 qa01 = __half22float2(qA.h2[0]);
    float2 qa23 = __half22float2(qA.h2[1]);
    float2 ka01 = __half22float2(kA.h2[0]);
    float2 ka23 = __half22float2(kA.h2[1]);
    float pA = qa01.x * wA.x * ka01.x + qa01.y * wA.y * ka01.y +
               qa23.x * wA.z * ka23.x + qa23.y * wA.w * ka23.y;
    float2 qb01 = __half22float2(qB.h2[0]);
    float2 qb23 = __half22float2(qB.h2[1]);
    float2 kb01 = __half22float2(kB.h2[0]);
    float2 kb23 = __half22float2(kB.h2[1]);
    float pB = qb01.x * wB.x * kb01.x + qb01.y * wB.y * kb01.y +
               qb23.x * wB.z * kb23.x + qb23.y * wB.w * kb23.y;

    pA += __shfl_xor(pA, 1);
    pB += __shfl_xor(pB, 1);
    pA += __shfl_xor(pA, 2);
    pB += __shfl_xor(pB, 2);
    pA += __shfl_xor(pA, 4);
    pB += __shfl_xor(pB, 4);
    float amA = __shfl(pA * cutA, srcLane);
    float amB = __shfl(pB * cutB, srcLane);
    if (lane < 16) {
      atomicAdd(out + (size_t)dstA * MTOT + midx, amA * spA);
      atomicAdd(out + (size_t)dstB * MTOT + midx, amB * spB);
    }
  }
  for (; e < E; e += ngroups) {
    int src = ei[e];
    int dst = ei[E + e];
    float cut = cutoff[e];
    vfloat4 w4 = __builtin_nontemporal_load(
        (const vfloat4*)(w_ij + (size_t)e * HIDDEN) + lane);
    union { uint2 u; __half2 h2[2]; } qa, ka;
    qa.u = *((const uint2*)(q + (size_t)dst * HIDDEN) + lane);
    ka.u = *((const uint2*)(k + (size_t)src * HIDDEN) + lane);
    float sp = __builtin_nontemporal_load(sph + (size_t)e * MTOT + midx);
    float2 q01 = __half22float2(qa.h2[0]);
    float2 q23 = __half22float2(qa.h2[1]);
    float2 k01 = __half22float2(ka.h2[0]);
    float2 k23 = __half22float2(ka.h2[1]);
    float p = q01.x * w4.x * k01.x + q01.y * w4.y * k01.y +
              q23.x * w4.z * k23.x + q23.y * w4.w * k23.y;
    p += __shfl_xor(p, 1);
    p += __shfl_xor(p, 2);
    p += __shfl_xor(p, 4);
    float am = __shfl(p * cut, srcLane);
    if (lane < 16) {
      atomicAdd(out + (size_t)dst * MTOT + midx, am * sp);
    }
  }
}

extern "C" void kernel_launch(void* const* d_in, const int* in_sizes, int n_in,
                              void* d_out, int out_size, void* d_ws, size_t ws_size,
                              hipStream_t stream) {
  // inputs: chi, sph_ij, x, w_ij, edge_index, cutoff, Wq, Wk
  const float* sph    = (const float*)d_in[1];
  const float* x      = (const float*)d_in[2];
  const float* w_ij   = (const float*)d_in[3];
  const int*   ei     = (const int*)d_in[4];
  const float* cutoff = (const float*)d_in[5];
  const float* Wq     = (const float*)d_in[6];
  const float* Wk     = (const float*)d_in[7];
  float* out = (float*)d_out;

  const int n_nodes = in_sizes[0] / MTOT;  // chi is [N, 16]
  const int E       = in_sizes[5];         // cutoff is [E, 1]

  // ws: q fp16 (12.8MB) | k fp16 (12.8MB) | Wh (64KB)
  __half* q  = (__half*)d_ws;
  __half* k  = q + (size_t)n_nodes * HIDDEN;
  __half* Wh = k + (size_t)n_nodes * HIDDEN;

  const int n4 = out_size / 4;
  zero_kernel<<<256, 256, 0, stream>>>((float4*)out, n4);

  const float inv_sqrt_hd = 0.17677669529663687f;  // 1/sqrt(32)
  cvt_w_kernel<<<128, 256, 0, stream>>>(Wq, Wk, Wh, inv_sqrt_hd);

  const int pgrid = (n_nodes + 63) / 64;
  proj_mfma_kernel<<<pgrid, 256, 0, stream>>>(x, Wh, q, k, n_nodes);

  const int NB = 40000;  // 320000 groups, 5 edges each
  const int ngroups = NB * 8;
  edge_kernel<<<NB, 256, 0, stream>>>(q, k, w_ij, sph, ei, cutoff, out, E,
                                      ngroups, NB / 8);
}